// Round 1
// baseline (552.156 us; speedup 1.0000x reference)
//
#include <hip/hip_runtime.h>

#define EPSN 1e-8f

typedef _Float16 half8 __attribute__((ext_vector_type(8)));
typedef float floatx4 __attribute__((ext_vector_type(4)));

// ---------------- K1: vis inverse norms (wave per row) ----------------
__global__ __launch_bounds__(256) void k_vinv(const float* __restrict__ vis,
                                              float* __restrict__ vinv) {
    int row  = blockIdx.x * 4 + (threadIdx.x >> 6);   // 8192 rows total
    int lane = threadIdx.x & 63;
    const float4* src = reinterpret_cast<const float4*>(vis + (size_t)row * 512);
    float4 a = src[lane];
    float4 b = src[lane + 64];
    float s = a.x*a.x + a.y*a.y + a.z*a.z + a.w*a.w
            + b.x*b.x + b.y*b.y + b.z*b.z + b.w*b.w;
    #pragma unroll
    for (int off = 1; off < 64; off <<= 1) s += __shfl_xor(s, off);
    if (lane == 0) vinv[row] = 1.0f / fmaxf(sqrtf(s), EPSN);
}

// ---------------- K2: per-(b,p,tblock) GEMM + exp-sums ----------------
// WG tile: 512 v  x 128 t, K=512 in chunks of 32. 8 waves, wave tile 64x128.
#define LDA 40   // padded halfs per A row (80B: 16B-aligned, conflict-light)
#define LDB 40

__global__ __launch_bounds__(512, 2) void k_main(
    const float* __restrict__ vis, const float* __restrict__ text,
    const float* __restrict__ vinv,
    float* __restrict__ g_rowsum, float* __restrict__ g_colsum,
    float* __restrict__ g_dsum)
{
    __shared__ _Float16 Ash[512 * LDA];   // 40 KB
    __shared__ _Float16 Bsh[128 * LDB];   // 10 KB
    __shared__ float tn2[128];
    __shared__ float colS[128];

    const int blk  = blockIdx.x;
    const int tb   = blk & 3;
    const int p    = (blk >> 2) & 15;
    const int b    = blk >> 6;
    const int bp   = blk >> 2;          // b*16 + p
    const int tid  = threadIdx.x;
    const int lane = tid & 63;
    const int wave = tid >> 6;
    const int t0   = tb * 128;
    const int m15  = lane & 15;
    const int g4   = lane >> 4;

    if (tid < 128) { tn2[tid] = 0.f; colS[tid] = 0.f; }
    __syncthreads();

    floatx4 acc[4][8];
    floatx4 zf = {0.f, 0.f, 0.f, 0.f};
    #pragma unroll
    for (int mb = 0; mb < 4; ++mb)
        #pragma unroll
        for (int nb = 0; nb < 8; ++nb) acc[mb][nb] = zf;

    const float* visB = vis + (size_t)b * 512 * 512;
    const int brow = tid >> 2;            // 0..127
    const int bko  = (tid & 3) * 8;       // 0,8,16,24
    const float* textRow =
        text + ((size_t)((b * 512 + t0 + brow) * 16 + p)) * 512;

    for (int kc = 0; kc < 16; ++kc) {
        const int k0 = kc * 32;
        // ---- stage A: vis 512x32 f32 -> f16 ----
        #pragma unroll
        for (int c = 0; c < 4; ++c) {
            int g   = c * 512 + tid;
            int row = g >> 2;
            int ko  = (g & 3) * 8;
            const float4* s4 =
                reinterpret_cast<const float4*>(visB + (size_t)row * 512 + k0 + ko);
            float4 f0 = s4[0], f1 = s4[1];
            half8 h = { (_Float16)f0.x, (_Float16)f0.y, (_Float16)f0.z, (_Float16)f0.w,
                        (_Float16)f1.x, (_Float16)f1.y, (_Float16)f1.z, (_Float16)f1.w };
            *reinterpret_cast<half8*>(&Ash[row * LDA + ko]) = h;
        }
        // ---- stage B: text 128x32 f32 -> f16, + row-norm accumulation ----
        {
            const float4* s4 = reinterpret_cast<const float4*>(textRow + k0 + bko);
            float4 f0 = s4[0], f1 = s4[1];
            float sq = f0.x*f0.x + f0.y*f0.y + f0.z*f0.z + f0.w*f0.w
                     + f1.x*f1.x + f1.y*f1.y + f1.z*f1.z + f1.w*f1.w;
            sq += __shfl_xor(sq, 1);
            sq += __shfl_xor(sq, 2);
            if ((lane & 3) == 0) atomicAdd(&tn2[brow], sq);
            half8 h = { (_Float16)f0.x, (_Float16)f0.y, (_Float16)f0.z, (_Float16)f0.w,
                        (_Float16)f1.x, (_Float16)f1.y, (_Float16)f1.z, (_Float16)f1.w };
            *reinterpret_cast<half8*>(&Bsh[brow * LDB + bko]) = h;
        }
        __syncthreads();
        // ---- MFMA: wave covers rows [64*wave, 64*wave+64), all 128 cols ----
        half8 af[4];
        #pragma unroll
        for (int mb = 0; mb < 4; ++mb)
            af[mb] = *reinterpret_cast<const half8*>(
                &Ash[(wave * 64 + mb * 16 + m15) * LDA + g4 * 8]);
        #pragma unroll
        for (int nb = 0; nb < 8; ++nb) {
            half8 bf = *reinterpret_cast<const half8*>(
                &Bsh[(nb * 16 + m15) * LDB + g4 * 8]);
            #pragma unroll
            for (int mb = 0; mb < 4; ++mb)
                acc[mb][nb] = __builtin_amdgcn_mfma_f32_16x16x32_f16(
                    af[mb], bf, acc[mb][nb], 0, 0, 0);
        }
        __syncthreads();
    }

    // tinv in place
    if (tid < 128) tn2[tid] = 1.0f / fmaxf(sqrtf(tn2[tid]), EPSN);
    __syncthreads();

    float tinvc[8];
    #pragma unroll
    for (int nb = 0; nb < 8; ++nb) tinvc[nb] = tn2[nb * 16 + m15];

    float colpart[8];
    #pragma unroll
    for (int nb = 0; nb < 8; ++nb) colpart[nb] = 0.f;
    float dsum = 0.f;

    // epilogue: scale, exp, row/col partial sums
    #pragma unroll
    for (int mb = 0; mb < 4; ++mb) {
        #pragma unroll
        for (int r = 0; r < 4; ++r) {
            int vglob = wave * 64 + mb * 16 + g4 * 4 + r;   // C/D row mapping
            float vi  = vinv[b * 512 + vglob];
            float rp  = 0.f;
            #pragma unroll
            for (int nb = 0; nb < 8; ++nb) {
                float sim  = acc[mb][nb][r] * vi * tinvc[nb];
                int tglob  = t0 + nb * 16 + m15;             // C/D col mapping
                if (vglob == tglob) dsum += sim;
                float e = __expf(sim);
                rp += e;
                colpart[nb] += e;
            }
            // reduce over the 16 cols held by lanes sharing this row
            rp += __shfl_xor(rp, 1);
            rp += __shfl_xor(rp, 2);
            rp += __shfl_xor(rp, 4);
            rp += __shfl_xor(rp, 8);
            if (m15 == 0)
                atomicAdd(&g_rowsum[(size_t)bp * 512 + vglob], rp);
        }
    }
    // col partials: reduce over the 4 lane-groups (rows), then LDS-accumulate
    #pragma unroll
    for (int nb = 0; nb < 8; ++nb) {
        float cp = colpart[nb];
        cp += __shfl_xor(cp, 16);
        cp += __shfl_xor(cp, 32);
        if (lane < 16) atomicAdd(&colS[nb * 16 + lane], cp);
    }
    #pragma unroll
    for (int off = 1; off < 64; off <<= 1) dsum += __shfl_xor(dsum, off);
    if (lane == 0) atomicAdd(&g_dsum[bp], dsum);
    __syncthreads();
    if (tid < 128)
        g_colsum[(size_t)bp * 512 + t0 + tid] = colS[tid];   // WG-exclusive t's
}

// ---------------- K3: per-(b,p) clip loss ----------------
__global__ __launch_bounds__(256) void k_clip(
    const float* __restrict__ g_rowsum, const float* __restrict__ g_colsum,
    const float* __restrict__ g_dsum, float* __restrict__ clip)
{
    __shared__ float red[4];
    int bp = blockIdx.x, tid = threadIdx.x;
    int lane = tid & 63, wave = tid >> 6;
    float s = 0.f;
    #pragma unroll
    for (int c = 0; c < 2; ++c) {
        int i = c * 256 + tid;
        s += 0.5f * (logf(g_rowsum[(size_t)bp * 512 + i]) +
                     logf(g_colsum[(size_t)bp * 512 + i]));
    }
    #pragma unroll
    for (int off = 1; off < 64; off <<= 1) s += __shfl_xor(s, off);
    if (lane == 0) red[wave] = s;
    __syncthreads();
    if (tid == 0)
        clip[bp] = (red[0] + red[1] + red[2] + red[3] - g_dsum[bp]) * (1.0f / 512.0f);
}

// ---------------- K4: loss / acc / preds ----------------
__global__ __launch_bounds__(256) void k_final(
    const float* __restrict__ clip, const float* __restrict__ output,
    float* __restrict__ out)
{
    __shared__ float cl[256], ou[256], red[4];
    __shared__ int preds[16];
    int tid = threadIdx.x, lane = tid & 63, wave = tid >> 6;
    cl[tid] = clip[tid];
    ou[tid] = output[tid];
    __syncthreads();
    float d = ou[tid] - cl[tid];
    float s = d * d;
    #pragma unroll
    for (int off = 1; off < 64; off <<= 1) s += __shfl_xor(s, off);
    if (lane == 0) red[wave] = s;
    if (tid < 16) {   // preds = argmin over output row (first occurrence)
        float m = ou[tid * 16]; int a = 0;
        for (int q = 1; q < 16; ++q)
            if (ou[tid * 16 + q] < m) { m = ou[tid * 16 + q]; a = q; }
        preds[tid] = a;
    }
    __syncthreads();
    if (tid == 0) {
        int cnt = 0;
        for (int bb = 0; bb < 16; ++bb) {
            float m = cl[bb * 16]; int a = 0;
            for (int q = 1; q < 16; ++q)
                if (cl[bb * 16 + q] < m) { m = cl[bb * 16 + q]; a = q; }
            cnt += (preds[bb] == a);
        }
        out[0] = (red[0] + red[1] + red[2] + red[3]) * (1.0f / 256.0f);
        out[1] = (float)cnt * (100.0f / 16.0f);
    }
    __syncthreads();
    for (int j = tid; j < 16 * 512; j += 256)
        out[2 + j] = (float)preds[j >> 9];
}

extern "C" void kernel_launch(void* const* d_in, const int* in_sizes, int n_in,
                              void* d_out, int out_size, void* d_ws, size_t ws_size,
                              hipStream_t stream)
{
    const float* output = (const float*)d_in[0];   // (16,16)
    const float* text   = (const float*)d_in[1];   // (16,512,16,512)
    const float* vis    = (const float*)d_in[2];   // (16,512,512)

    float* g_rowsum = (float*)d_ws;                // 256*512
    float* g_dsum   = g_rowsum + 256 * 512;        // 256
    float* g_colsum = g_dsum + 256;                // 256*512
    float* clip     = g_colsum + 256 * 512;        // 256
    float* vinv     = clip + 256;                  // 8192
    // zero rowsum + dsum (atomic accumulation targets); rest is overwritten
    hipMemsetAsync(d_ws, 0, (size_t)(256 * 512 + 256) * sizeof(float), stream);

    k_vinv <<<2048, 256, 0, stream>>>(vis, vinv);
    k_main <<<1024, 512, 0, stream>>>(vis, text, vinv, g_rowsum, g_colsum, g_dsum);
    k_clip <<<256, 256, 0, stream>>>(g_rowsum, g_colsum, g_dsum, clip);
    k_final<<<1, 256, 0, stream>>>(clip, output, (float*)d_out);
}

// Round 2
// 482.648 us; speedup vs baseline: 1.1440x; 1.1440x over previous
//
#include <hip/hip_runtime.h>

#define EPSN 1e-8f

typedef _Float16 half8 __attribute__((ext_vector_type(8)));
typedef float floatx4 __attribute__((ext_vector_type(4)));

// ---------------- K1: vis inverse norms (wave per row) ----------------
__global__ __launch_bounds__(256) void k_vinv(const float* __restrict__ vis,
                                              float* __restrict__ vinv) {
    int row  = blockIdx.x * 4 + (threadIdx.x >> 6);   // 8192 rows total
    int lane = threadIdx.x & 63;
    const float4* src = reinterpret_cast<const float4*>(vis + (size_t)row * 512);
    float4 a = src[lane];
    float4 b = src[lane + 64];
    float s = a.x*a.x + a.y*a.y + a.z*a.z + a.w*a.w
            + b.x*b.x + b.y*b.y + b.z*b.z + b.w*b.w;
    #pragma unroll
    for (int off = 1; off < 64; off <<= 1) s += __shfl_xor(s, off);
    if (lane == 0) vinv[row] = 1.0f / fmaxf(sqrtf(s), EPSN);
}

// ---------------- K2: per-(b,p,tblock,vhalf) GEMM + exp-sums ----------------
// WG: 256 threads (4 waves), tile 256 v x 128 t, K=512 in chunks of 32.
// Wave tile 64x128 (acc = 128 regs). Two 4-wave blocks co-resident per CU
// give barrier-independent overlap (vs one 8-wave block fully synchronized).
#define LDA 40   // padded halfs per row (80 B: 16B-aligned, 2-way-only conflicts)
#define LDB 40

__global__ __launch_bounds__(256, 2) void k_main(
    const float* __restrict__ vis, const float* __restrict__ text,
    const float* __restrict__ vinv,
    float* __restrict__ g_rowsum, float* __restrict__ g_colsum,
    float* __restrict__ g_dsum)
{
    __shared__ _Float16 Ash[256 * LDA];   // 20 KB
    __shared__ _Float16 Bsh[128 * LDB];   // 10 KB
    __shared__ float tn2[128];
    __shared__ float colS[128];

    const int blk  = blockIdx.x;          // (((b*16+p)*4+tb)*2+vh)
    const int vh   = blk & 1;
    const int tb   = (blk >> 1) & 3;
    const int bp   = blk >> 3;            // b*16 + p
    const int p    = bp & 15;
    const int b    = bp >> 4;
    const int tid  = threadIdx.x;
    const int lane = tid & 63;
    const int wave = tid >> 6;
    const int v0   = vh * 256;
    const int t0   = tb * 128;
    const int m15  = lane & 15;
    const int g4   = lane >> 4;

    if (tid < 128) colS[tid] = 0.f;       // first in-loop barrier orders this

    floatx4 acc[4][8];
    floatx4 zf = {0.f, 0.f, 0.f, 0.f};
    #pragma unroll
    for (int mb = 0; mb < 4; ++mb)
        #pragma unroll
        for (int nb = 0; nb < 8; ++nb) acc[mb][nb] = zf;

    const float* visB = vis + (size_t)b * 512 * 512 + (size_t)v0 * 512;
    const int arow = tid >> 2;            // A row (per c-iter: c*64 + arow)
    const int ako  = (tid & 3) * 8;
    const int brow0 = tid >> 2;           // 0..63
    const int brow1 = 64 + (tid >> 2);    // 64..127
    const int bko  = (tid & 3) * 8;
    const float* textRow0 =
        text + ((size_t)((b * 512 + t0 + brow0) * 16 + p)) * 512;
    const float* textRow1 =
        text + ((size_t)((b * 512 + t0 + brow1) * 16 + p)) * 512;

    float sq0 = 0.f, sq1 = 0.f;           // text row-norm partials (regs, not LDS)

    for (int kc = 0; kc < 16; ++kc) {
        const int k0 = kc * 32;
        // ---- stage A: vis 256x32 f32 -> f16 ----
        #pragma unroll
        for (int c = 0; c < 4; ++c) {
            int row = c * 64 + arow;
            const float4* s4 =
                reinterpret_cast<const float4*>(visB + (size_t)row * 512 + k0 + ako);
            float4 f0 = s4[0], f1 = s4[1];
            half8 h = { (_Float16)f0.x, (_Float16)f0.y, (_Float16)f0.z, (_Float16)f0.w,
                        (_Float16)f1.x, (_Float16)f1.y, (_Float16)f1.z, (_Float16)f1.w };
            *reinterpret_cast<half8*>(&Ash[row * LDA + ako]) = h;
        }
        // ---- stage B: text 128x32 f32 -> f16 (two 64-row slabs/thread) ----
        {
            const float4* s4 = reinterpret_cast<const float4*>(textRow0 + k0 + bko);
            float4 f0 = s4[0], f1 = s4[1];
            sq0 += f0.x*f0.x + f0.y*f0.y + f0.z*f0.z + f0.w*f0.w
                 + f1.x*f1.x + f1.y*f1.y + f1.z*f1.z + f1.w*f1.w;
            half8 h = { (_Float16)f0.x, (_Float16)f0.y, (_Float16)f0.z, (_Float16)f0.w,
                        (_Float16)f1.x, (_Float16)f1.y, (_Float16)f1.z, (_Float16)f1.w };
            *reinterpret_cast<half8*>(&Bsh[brow0 * LDB + bko]) = h;
        }
        {
            const float4* s4 = reinterpret_cast<const float4*>(textRow1 + k0 + bko);
            float4 f0 = s4[0], f1 = s4[1];
            sq1 += f0.x*f0.x + f0.y*f0.y + f0.z*f0.z + f0.w*f0.w
                 + f1.x*f1.x + f1.y*f1.y + f1.z*f1.z + f1.w*f1.w;
            half8 h = { (_Float16)f0.x, (_Float16)f0.y, (_Float16)f0.z, (_Float16)f0.w,
                        (_Float16)f1.x, (_Float16)f1.y, (_Float16)f1.z, (_Float16)f1.w };
            *reinterpret_cast<half8*>(&Bsh[brow1 * LDB + bko]) = h;
        }
        __syncthreads();
        // ---- MFMA: wave covers rows [64*wave, 64*wave+64), all 128 cols ----
        half8 af[4];
        #pragma unroll
        for (int mb = 0; mb < 4; ++mb)
            af[mb] = *reinterpret_cast<const half8*>(
                &Ash[(wave * 64 + mb * 16 + m15) * LDA + g4 * 8]);
        #pragma unroll
        for (int nb = 0; nb < 8; ++nb) {
            half8 bf = *reinterpret_cast<const half8*>(
                &Bsh[(nb * 16 + m15) * LDB + g4 * 8]);
            #pragma unroll
            for (int mb = 0; mb < 4; ++mb)
                acc[mb][nb] = __builtin_amdgcn_mfma_f32_16x16x32_f16(
                    af[mb], bf, acc[mb][nb], 0, 0, 0);
        }
        __syncthreads();
    }

    // text inverse norms: reduce per 4-lane group, plain store (rows unique)
    sq0 += __shfl_xor(sq0, 1); sq0 += __shfl_xor(sq0, 2);
    sq1 += __shfl_xor(sq1, 1); sq1 += __shfl_xor(sq1, 2);
    if ((tid & 3) == 0) {
        tn2[brow0] = 1.0f / fmaxf(sqrtf(sq0), EPSN);
        tn2[brow1] = 1.0f / fmaxf(sqrtf(sq1), EPSN);
    }
    __syncthreads();

    float tinvc[8];
    #pragma unroll
    for (int nb = 0; nb < 8; ++nb) tinvc[nb] = tn2[nb * 16 + m15];

    float colpart[8];
    #pragma unroll
    for (int nb = 0; nb < 8; ++nb) colpart[nb] = 0.f;
    float dsum = 0.f;

    // epilogue: scale, exp, row/col partial sums
    #pragma unroll
    for (int mb = 0; mb < 4; ++mb) {
        #pragma unroll
        for (int r = 0; r < 4; ++r) {
            int vglob = v0 + wave * 64 + mb * 16 + g4 * 4 + r;   // C/D row mapping
            float vi  = vinv[b * 512 + vglob];
            float rp  = 0.f;
            #pragma unroll
            for (int nb = 0; nb < 8; ++nb) {
                float sim  = acc[mb][nb][r] * vi * tinvc[nb];
                int tglob  = t0 + nb * 16 + m15;                 // C/D col mapping
                if (vglob == tglob) dsum += sim;
                float e = __expf(sim);
                rp += e;
                colpart[nb] += e;
            }
            rp += __shfl_xor(rp, 1);
            rp += __shfl_xor(rp, 2);
            rp += __shfl_xor(rp, 4);
            rp += __shfl_xor(rp, 8);
            if (m15 == 0)
                atomicAdd(&g_rowsum[(size_t)bp * 512 + vglob], rp);
        }
    }
    // col partials: reduce over the 4 lane-groups (rows), then LDS-accumulate
    #pragma unroll
    for (int nb = 0; nb < 8; ++nb) {
        float cp = colpart[nb];
        cp += __shfl_xor(cp, 16);
        cp += __shfl_xor(cp, 32);
        if (lane < 16) atomicAdd(&colS[nb * 16 + lane], cp);
    }
    #pragma unroll
    for (int off = 1; off < 64; off <<= 1) dsum += __shfl_xor(dsum, off);
    if (lane == 0) atomicAdd(&g_dsum[bp], dsum);
    __syncthreads();
    if (tid < 128)   // two v-half WGs share this t-range now -> atomic
        atomicAdd(&g_colsum[(size_t)bp * 512 + t0 + tid], colS[tid]);
}

// ---------------- K3: per-(b,p) clip loss ----------------
__global__ __launch_bounds__(256) void k_clip(
    const float* __restrict__ g_rowsum, const float* __restrict__ g_colsum,
    const float* __restrict__ g_dsum, float* __restrict__ clip)
{
    __shared__ float red[4];
    int bp = blockIdx.x, tid = threadIdx.x;
    int lane = tid & 63, wave = tid >> 6;
    float s = 0.f;
    #pragma unroll
    for (int c = 0; c < 2; ++c) {
        int i = c * 256 + tid;
        s += 0.5f * (logf(g_rowsum[(size_t)bp * 512 + i]) +
                     logf(g_colsum[(size_t)bp * 512 + i]));
    }
    #pragma unroll
    for (int off = 1; off < 64; off <<= 1) s += __shfl_xor(s, off);
    if (lane == 0) red[wave] = s;
    __syncthreads();
    if (tid == 0)
        clip[bp] = (red[0] + red[1] + red[2] + red[3] - g_dsum[bp]) * (1.0f / 512.0f);
}

// ---------------- K4: loss / acc / preds ----------------
__global__ __launch_bounds__(256) void k_final(
    const float* __restrict__ clip, const float* __restrict__ output,
    float* __restrict__ out)
{
    __shared__ float cl[256], ou[256], red[4];
    __shared__ int preds[16];
    int tid = threadIdx.x, lane = tid & 63, wave = tid >> 6;
    cl[tid] = clip[tid];
    ou[tid] = output[tid];
    __syncthreads();
    float d = ou[tid] - cl[tid];
    float s = d * d;
    #pragma unroll
    for (int off = 1; off < 64; off <<= 1) s += __shfl_xor(s, off);
    if (lane == 0) red[wave] = s;
    if (tid < 16) {   // preds = argmin over output row (first occurrence)
        float m = ou[tid * 16]; int a = 0;
        for (int q = 1; q < 16; ++q)
            if (ou[tid * 16 + q] < m) { m = ou[tid * 16 + q]; a = q; }
        preds[tid] = a;
    }
    __syncthreads();
    if (tid == 0) {
        int cnt = 0;
        for (int bb = 0; bb < 16; ++bb) {
            float m = cl[bb * 16]; int a = 0;
            for (int q = 1; q < 16; ++q)
                if (cl[bb * 16 + q] < m) { m = cl[bb * 16 + q]; a = q; }
            cnt += (preds[bb] == a);
        }
        out[0] = (red[0] + red[1] + red[2] + red[3]) * (1.0f / 256.0f);
        out[1] = (float)cnt * (100.0f / 16.0f);
    }
    __syncthreads();
    for (int j = tid; j < 16 * 512; j += 256)
        out[2 + j] = (float)preds[j >> 9];
}

extern "C" void kernel_launch(void* const* d_in, const int* in_sizes, int n_in,
                              void* d_out, int out_size, void* d_ws, size_t ws_size,
                              hipStream_t stream)
{
    const float* output = (const float*)d_in[0];   // (16,16)
    const float* text   = (const float*)d_in[1];   // (16,512,16,512)
    const float* vis    = (const float*)d_in[2];   // (16,512,512)

    float* g_rowsum = (float*)d_ws;                // 256*512
    float* g_colsum = g_rowsum + 256 * 512;        // 256*512
    float* g_dsum   = g_colsum + 256 * 512;        // 256
    float* clip     = g_dsum + 256;                // 256
    float* vinv     = clip + 256;                  // 8192
    // zero rowsum + colsum + dsum (atomic accumulation targets)
    hipMemsetAsync(d_ws, 0, (size_t)(2 * 256 * 512 + 256) * sizeof(float), stream);

    k_vinv <<<2048, 256, 0, stream>>>(vis, vinv);
    k_main <<<2048, 256, 0, stream>>>(vis, text, vinv, g_rowsum, g_colsum, g_dsum);
    k_clip <<<256, 256, 0, stream>>>(g_rowsum, g_colsum, g_dsum, clip);
    k_final<<<1, 256, 0, stream>>>(clip, output, (float*)d_out);
}

// Round 4
// 476.102 us; speedup vs baseline: 1.1597x; 1.0138x over previous
//
#include <hip/hip_runtime.h>

#define EPSN 1e-8f

typedef _Float16 half8 __attribute__((ext_vector_type(8)));
typedef __fp16 fp16x2 __attribute__((ext_vector_type(2)));   // cvt_pkrtz result type
typedef float floatx4 __attribute__((ext_vector_type(4)));

// ---------------- K2: per-(b,p,tblock,vhalf) GEMM + exp-sums ----------------
// WG: 256 threads (4 waves), tile 256 v x 128 t, K=512 in chunks of 32.
// Wave tile 64x128 (acc = 128 regs). Two 4-wave blocks co-resident per CU.
// Software pipeline: chunk k+1's global loads are issued (to registers)
// during chunk k's cvt+LDS-write, so their vmcnt wait lands after
// barrier+MFMA(k)+barrier instead of stalling the staging phase.
// vis row norms are computed inline during A staging (k_vinv deleted).
#define LDA 40   // padded halfs per row (80 B: 16B-aligned, 2-way-only conflicts)
#define LDB 40

__global__ __launch_bounds__(256, 2) void k_main(
    const float* __restrict__ vis, const float* __restrict__ text,
    float* __restrict__ g_rowsum, float* __restrict__ g_colsum,
    float* __restrict__ g_dsum)
{
    __shared__ _Float16 Ash[256 * LDA];   // 20 KB
    __shared__ _Float16 Bsh[128 * LDB];   // 10 KB
    __shared__ float tn2[128];
    __shared__ float vinvS[256];
    __shared__ float colS[128];

    const int blk  = blockIdx.x;          // (((b*16+p)*4+tb)*2+vh)
    const int vh   = blk & 1;
    const int tb   = (blk >> 1) & 3;
    const int bp   = blk >> 3;            // b*16 + p
    const int p    = bp & 15;
    const int b    = bp >> 4;
    const int tid  = threadIdx.x;
    const int lane = tid & 63;
    const int wave = tid >> 6;
    const int v0   = vh * 256;
    const int t0   = tb * 128;
    const int m15  = lane & 15;
    const int g4   = lane >> 4;

    if (tid < 128) colS[tid] = 0.f;       // first in-loop barrier orders this

    floatx4 acc[4][8];
    floatx4 zf = {0.f, 0.f, 0.f, 0.f};
    #pragma unroll
    for (int mb = 0; mb < 4; ++mb)
        #pragma unroll
        for (int nb = 0; nb < 8; ++nb) acc[mb][nb] = zf;

    const float* visB = vis + (size_t)b * 512 * 512 + (size_t)v0 * 512;
    const int arow = tid >> 2;            // 0..63 (A row within c-slab)
    const int ako  = (tid & 3) * 8;
    const float* aBase = visB + (size_t)arow * 512 + ako;
    const float* tPtr0 =
        text + ((size_t)((b * 512 + t0 + (tid >> 2)) * 16 + p)) * 512 + (tid & 3) * 8;
    const float* tPtr1 = tPtr0 + (size_t)64 * 16 * 512;

    float vsq[4] = {0.f, 0.f, 0.f, 0.f};  // vis row-norm partials
    float sq0 = 0.f, sq1 = 0.f;           // text row-norm partials

    // -------- prologue: issue chunk-0 loads --------
    float4 abuf[4][2];
    #pragma unroll
    for (int c = 0; c < 4; ++c) {
        abuf[c][0] = *reinterpret_cast<const float4*>(aBase + c * 64 * 512);
        abuf[c][1] = *reinterpret_cast<const float4*>(aBase + c * 64 * 512 + 4);
    }
    float4 bbuf[2][2];
    bbuf[0][0] = *reinterpret_cast<const float4*>(tPtr0);
    bbuf[0][1] = *reinterpret_cast<const float4*>(tPtr0 + 4);
    bbuf[1][0] = *reinterpret_cast<const float4*>(tPtr1);
    bbuf[1][1] = *reinterpret_cast<const float4*>(tPtr1 + 4);

    for (int kc = 0; kc < 16; ++kc) {
        const int kn = ((kc + 1) & 15) * 32;   // next chunk (wraps harmlessly)
        // ---- stage A: cvt buffered chunk -> LDS, issue next chunk's loads ----
        #pragma unroll
        for (int c = 0; c < 4; ++c) {
            float4 f0 = abuf[c][0], f1 = abuf[c][1];
            vsq[c] += f0.x*f0.x + f0.y*f0.y + f0.z*f0.z + f0.w*f0.w
                    + f1.x*f1.x + f1.y*f1.y + f1.z*f1.z + f1.w*f1.w;
            union { half8 v; fp16x2 p[4]; } u;
            u.p[0] = __builtin_amdgcn_cvt_pkrtz(f0.x, f0.y);
            u.p[1] = __builtin_amdgcn_cvt_pkrtz(f0.z, f0.w);
            u.p[2] = __builtin_amdgcn_cvt_pkrtz(f1.x, f1.y);
            u.p[3] = __builtin_amdgcn_cvt_pkrtz(f1.z, f1.w);
            *reinterpret_cast<half8*>(&Ash[(c * 64 + arow) * LDA + ako]) = u.v;
            abuf[c][0] = *reinterpret_cast<const float4*>(aBase + c * 64 * 512 + kn);
            abuf[c][1] = *reinterpret_cast<const float4*>(aBase + c * 64 * 512 + kn + 4);
        }
        // ---- stage B: two 64-row slabs ----
        {
            float4 f0 = bbuf[0][0], f1 = bbuf[0][1];
            sq0 += f0.x*f0.x + f0.y*f0.y + f0.z*f0.z + f0.w*f0.w
                 + f1.x*f1.x + f1.y*f1.y + f1.z*f1.z + f1.w*f1.w;
            union { half8 v; fp16x2 p[4]; } u;
            u.p[0] = __builtin_amdgcn_cvt_pkrtz(f0.x, f0.y);
            u.p[1] = __builtin_amdgcn_cvt_pkrtz(f0.z, f0.w);
            u.p[2] = __builtin_amdgcn_cvt_pkrtz(f1.x, f1.y);
            u.p[3] = __builtin_amdgcn_cvt_pkrtz(f1.z, f1.w);
            *reinterpret_cast<half8*>(&Bsh[(tid >> 2) * LDB + (tid & 3) * 8]) = u.v;
            bbuf[0][0] = *reinterpret_cast<const float4*>(tPtr0 + kn);
            bbuf[0][1] = *reinterpret_cast<const float4*>(tPtr0 + kn + 4);
        }
        {
            float4 f0 = bbuf[1][0], f1 = bbuf[1][1];
            sq1 += f0.x*f0.x + f0.y*f0.y + f0.z*f0.z + f0.w*f0.w
                 + f1.x*f1.x + f1.y*f1.y + f1.z*f1.z + f1.w*f1.w;
            union { half8 v; fp16x2 p[4]; } u;
            u.p[0] = __builtin_amdgcn_cvt_pkrtz(f0.x, f0.y);
            u.p[1] = __builtin_amdgcn_cvt_pkrtz(f0.z, f0.w);
            u.p[2] = __builtin_amdgcn_cvt_pkrtz(f1.x, f1.y);
            u.p[3] = __builtin_amdgcn_cvt_pkrtz(f1.z, f1.w);
            *reinterpret_cast<half8*>(&Bsh[(64 + (tid >> 2)) * LDB + (tid & 3) * 8]) = u.v;
            bbuf[1][0] = *reinterpret_cast<const float4*>(tPtr1 + kn);
            bbuf[1][1] = *reinterpret_cast<const float4*>(tPtr1 + kn + 4);
        }
        __syncthreads();
        // ---- MFMA: wave covers rows [64*wave, 64*wave+64), all 128 cols ----
        half8 af[4];
        #pragma unroll
        for (int mb = 0; mb < 4; ++mb)
            af[mb] = *reinterpret_cast<const half8*>(
                &Ash[(wave * 64 + mb * 16 + m15) * LDA + g4 * 8]);
        #pragma unroll
        for (int nb = 0; nb < 8; ++nb) {
            half8 bf = *reinterpret_cast<const half8*>(
                &Bsh[(nb * 16 + m15) * LDB + g4 * 8]);
            #pragma unroll
            for (int mb = 0; mb < 4; ++mb)
                acc[mb][nb] = __builtin_amdgcn_mfma_f32_16x16x32_f16(
                    af[mb], bf, acc[mb][nb], 0, 0, 0);
        }
        __syncthreads();
    }

    // vis inverse norms (rows c*64 + arow), reduce over the 4 ako lanes
    #pragma unroll
    for (int c = 0; c < 4; ++c) {
        float s = vsq[c];
        s += __shfl_xor(s, 1); s += __shfl_xor(s, 2);
        if ((lane & 3) == 0)
            vinvS[c * 64 + arow] = 1.0f / fmaxf(sqrtf(s), EPSN);
    }
    // text inverse norms
    sq0 += __shfl_xor(sq0, 1); sq0 += __shfl_xor(sq0, 2);
    sq1 += __shfl_xor(sq1, 1); sq1 += __shfl_xor(sq1, 2);
    if ((tid & 3) == 0) {
        tn2[tid >> 2] = 1.0f / fmaxf(sqrtf(sq0), EPSN);
        tn2[64 + (tid >> 2)] = 1.0f / fmaxf(sqrtf(sq1), EPSN);
    }
    __syncthreads();

    float tinvc[8];
    #pragma unroll
    for (int nb = 0; nb < 8; ++nb) tinvc[nb] = tn2[nb * 16 + m15];

    float colpart[8];
    #pragma unroll
    for (int nb = 0; nb < 8; ++nb) colpart[nb] = 0.f;
    float dsum = 0.f;

    // epilogue: scale, exp, row/col partial sums
    #pragma unroll
    for (int mb = 0; mb < 4; ++mb) {
        #pragma unroll
        for (int r = 0; r < 4; ++r) {
            int vloc  = wave * 64 + mb * 16 + g4 * 4 + r;     // C/D row mapping
            int vglob = v0 + vloc;
            float vi  = vinvS[vloc];
            float rp  = 0.f;
            #pragma unroll
            for (int nb = 0; nb < 8; ++nb) {
                float sim  = acc[mb][nb][r] * vi * tinvc[nb];
                int tglob  = t0 + nb * 16 + m15;              // C/D col mapping
                if (vglob == tglob) dsum += sim;
                float e = __expf(sim);
                rp += e;
                colpart[nb] += e;
            }
            rp += __shfl_xor(rp, 1);
            rp += __shfl_xor(rp, 2);
            rp += __shfl_xor(rp, 4);
            rp += __shfl_xor(rp, 8);
            if (m15 == 0)
                atomicAdd(&g_rowsum[(size_t)bp * 512 + vglob], rp);
        }
    }
    // col partials: reduce over the 4 lane-groups (rows), then LDS-accumulate
    #pragma unroll
    for (int nb = 0; nb < 8; ++nb) {
        float cp = colpart[nb];
        cp += __shfl_xor(cp, 16);
        cp += __shfl_xor(cp, 32);
        if (lane < 16) atomicAdd(&colS[nb * 16 + lane], cp);
    }
    #pragma unroll
    for (int off = 1; off < 64; off <<= 1) dsum += __shfl_xor(dsum, off);
    if (lane == 0) atomicAdd(&g_dsum[bp], dsum);
    __syncthreads();
    if (tid < 128)   // two v-half WGs share this t-range -> atomic
        atomicAdd(&g_colsum[(size_t)bp * 512 + t0 + tid], colS[tid]);
}

// ---------------- K3: per-(b,p) clip loss ----------------
__global__ __launch_bounds__(256) void k_clip(
    const float* __restrict__ g_rowsum, const float* __restrict__ g_colsum,
    const float* __restrict__ g_dsum, float* __restrict__ clip)
{
    __shared__ float red[4];
    int bp = blockIdx.x, tid = threadIdx.x;
    int lane = tid & 63, wave = tid >> 6;
    float s = 0.f;
    #pragma unroll
    for (int c = 0; c < 2; ++c) {
        int i = c * 256 + tid;
        s += 0.5f * (logf(g_rowsum[(size_t)bp * 512 + i]) +
                     logf(g_colsum[(size_t)bp * 512 + i]));
    }
    #pragma unroll
    for (int off = 1; off < 64; off <<= 1) s += __shfl_xor(s, off);
    if (lane == 0) red[wave] = s;
    __syncthreads();
    if (tid == 0)
        clip[bp] = (red[0] + red[1] + red[2] + red[3] - g_dsum[bp]) * (1.0f / 512.0f);
}

// ---------------- K4: loss / acc / preds ----------------
__global__ __launch_bounds__(256) void k_final(
    const float* __restrict__ clip, const float* __restrict__ output,
    float* __restrict__ out)
{
    __shared__ float cl[256], ou[256], red[4];
    __shared__ int preds[16];
    int tid = threadIdx.x, lane = tid & 63, wave = tid >> 6;
    cl[tid] = clip[tid];
    ou[tid] = output[tid];
    __syncthreads();
    float d = ou[tid] - cl[tid];
    float s = d * d;
    #pragma unroll
    for (int off = 1; off < 64; off <<= 1) s += __shfl_xor(s, off);
    if (lane == 0) red[wave] = s;
    if (tid < 16) {   // preds = argmin over output row (first occurrence)
        float m = ou[tid * 16]; int a = 0;
        for (int q = 1; q < 16; ++q)
            if (ou[tid * 16 + q] < m) { m = ou[tid * 16 + q]; a = q; }
        preds[tid] = a;
    }
    __syncthreads();
    if (tid == 0) {
        int cnt = 0;
        for (int bb = 0; bb < 16; ++bb) {
            float m = cl[bb * 16]; int a = 0;
            for (int q = 1; q < 16; ++q)
                if (cl[bb * 16 + q] < m) { m = cl[bb * 16 + q]; a = q; }
            cnt += (preds[bb] == a);
        }
        out[0] = (red[0] + red[1] + red[2] + red[3]) * (1.0f / 256.0f);
        out[1] = (float)cnt * (100.0f / 16.0f);
    }
    __syncthreads();
    for (int j = tid; j < 16 * 512; j += 256)
        out[2 + j] = (float)preds[j >> 9];
}

extern "C" void kernel_launch(void* const* d_in, const int* in_sizes, int n_in,
                              void* d_out, int out_size, void* d_ws, size_t ws_size,
                              hipStream_t stream)
{
    const float* output = (const float*)d_in[0];   // (16,16)
    const float* text   = (const float*)d_in[1];   // (16,512,16,512)
    const float* vis    = (const float*)d_in[2];   // (16,512,512)

    float* g_rowsum = (float*)d_ws;                // 256*512
    float* g_colsum = g_rowsum + 256 * 512;        // 256*512
    float* g_dsum   = g_colsum + 256 * 512;        // 256
    float* clip     = g_dsum + 256;                // 256
    // zero rowsum + colsum + dsum (atomic accumulation targets)
    (void)hipMemsetAsync(d_ws, 0, (size_t)(2 * 256 * 512 + 256) * sizeof(float), stream);

    k_main <<<2048, 256, 0, stream>>>(vis, text, g_rowsum, g_colsum, g_dsum);
    k_clip <<<256, 256, 0, stream>>>(g_rowsum, g_colsum, g_dsum, clip);
    k_final<<<1, 256, 0, stream>>>(clip, output, (float*)d_out);
}